// Round 11
// baseline (484.568 us; speedup 1.0000x reference)
//
#include <hip/hip_runtime.h>
#include <cstdint>
#include <cstddef>

#define DEVFN __device__ __forceinline__
#define SCHEDB  __builtin_amdgcn_sched_barrier(0)
#define BARRIER __builtin_amdgcn_s_barrier()
#define LGKM0   asm volatile("s_waitcnt lgkmcnt(0)" ::: "memory")
#define WAITV(n) asm volatile("s_waitcnt vmcnt(" #n ")" ::: "memory")

typedef __attribute__((ext_vector_type(8))) __bf16 bf16x8;
typedef __attribute__((ext_vector_type(4))) float f32x4;

static constexpr int DM = 1024;
static constexpr int NH = 16;
static constexpr int HD = 64;
static constexpr int BATCH = 512;
static constexpr int SEQ = 64;
static constexpr int MROWS = BATCH * SEQ;   // 32768
static constexpr int KDIM = DM;             // 1024
static constexpr int NT = KDIM / 64;        // 16 k-tiles

DEVFN unsigned short f2bf(float f) {
  unsigned u = __builtin_bit_cast(unsigned, f);
  u += 0x7fffu + ((u >> 16) & 1u);   // RNE
  return (unsigned short)(u >> 16);
}

DEVFN void gload_lds16(const void* g, void* l) {
  __builtin_amdgcn_global_load_lds(
      (__attribute__((address_space(1))) const void*)g,
      (__attribute__((address_space(3))) void*)l, 16, 0, 0);
}

DEVFN unsigned ldsaddr(const void* p) {
  return (unsigned)(uintptr_t)(__attribute__((address_space(3))) const void*)p;
}

DEVFN bf16x8 ds128(unsigned off) {
  // opaque to alias analysis; ordering is OURS via vmcnt ledger + LGKM0+SCHEDB
  bf16x8 r;
  asm volatile("ds_read_b128 %0, %1" : "=v"(r) : "v"(off));
  return r;
}

// ------- one-shot fp32 -> bf16 convert of x + Wq|Wk|Wv|Wo into xb|wb -------
__global__ void convert_all_kernel(const float* __restrict__ x,
                                   const float* __restrict__ w0,
                                   const float* __restrict__ w1,
                                   const float* __restrict__ w2,
                                   const float* __restrict__ w3,
                                   unsigned short* __restrict__ dst) {
  const size_t NX = (size_t)MROWS * DM;
  const size_t NTOT = NX + 4ull * DM * DM;
  size_t i = ((size_t)blockIdx.x * blockDim.x + threadIdx.x) * 4;
  const size_t stride = (size_t)gridDim.x * blockDim.x * 4;
  for (; i < NTOT; i += stride) {
    const float* s;
    size_t off;
    if (i < NX) { s = x; off = i; }
    else {
      size_t j = i - NX;
      const int seg = (int)(j >> 20);
      off = j & ((1u << 20) - 1);
      s = (seg == 0) ? w0 : (seg == 1) ? w1 : (seg == 2) ? w2 : w3;
    }
    float4 f = *reinterpret_cast<const float4*>(s + off);
    ushort4 o;
    o.x = f2bf(f.x); o.y = f2bf(f.y); o.z = f2bf(f.z); o.w = f2bf(f.w);
    *reinterpret_cast<ushort4*>(dst + i) = o;
  }
}

// ---------------- RoPE cos/sin table: [SEQ][512] float2 ---------------------
__global__ void rope_table_kernel(float2* __restrict__ tab) {
  int idx = blockIdx.x * blockDim.x + threadIdx.x;
  if (idx >= SEQ * 512) return;
  int s = idx >> 9, i = idx & 511;
  float inv_freq = exp2f(-(float)i * (13.287712379549449f / 512.0f));
  float ang = (float)s * inv_freq;
  tab[idx] = make_float2(cosf(ang), sinf(ang));
}

#define PHASE_MFMA(MH, NH, AR, BR)                                        \
  __builtin_amdgcn_s_setprio(1);                                          \
  _Pragma("unroll")                                                       \
  for (int kk = 0; kk < 2; ++kk) {                                        \
    _Pragma("unroll")                                                     \
    for (int mi = 0; mi < 4; ++mi) {                                      \
      _Pragma("unroll")                                                   \
      for (int ni = 0; ni < 2; ++ni)                                      \
        acc[(MH)*4 + mi][(NH)*2 + ni] =                                   \
            __builtin_amdgcn_mfma_f32_16x16x32_bf16(                      \
                AR[mi][kk], BR[ni][kk], acc[(MH)*4 + mi][(NH)*2 + ni],    \
                0, 0, 0);                                                 \
    }                                                                     \
  }                                                                       \
  __builtin_amdgcn_s_setprio(0);

// ====== 256x256 GEMM, BK=64, 8 waves, quadrant-phase 8-phase schedule ======
// Half-tile unit = 128 ROWS x BK=64 (16KB, 128B rows) -- m201's BM/2 x BK.
// LDS [2 buf][2 rowhalf] per operand = 128 KiB. Banking = round-2's
// HW-verified ZERO-conflict pattern (write scol=((tid&7)^(srow&7))*8 via
// pre-swizzled global source; read koff=(kk*32+(l>>4)*8)^((l&7)*8)).
// Per tile, 4 quadrant-phases (mh,nh): {ds_read subtile || stage 1 unit ->
// barrier -> lgkm0 -> setprio 16 MFMA -> barrier}. Rotation:
//   p1 -> A.rh1(t+1)   p2 -> B.rh1(t+1)   (other buffer)
//   p3 -> A.rh0(t+2)   p4 -> B.rh0(t+2)   (current buffer; WAR barrier-safe)
// Single counted vmcnt(4) at p4 (2 units in flight) -- issue-ledger proves
// every unit is landed >=4 phases before its first read.
// Wave w (2M x 4N): output rows {mh*128 + wr*64 .. +63}, cols {nh*128 +
// wc*32 .. +31} per quadrant.
template <int MODE>
__global__ __launch_bounds__(512, 1)
void gemm8q_kernel(const unsigned short* __restrict__ A,
                   const unsigned short* __restrict__ Bw,
                   const float* __restrict__ bias0,
                   const float* __restrict__ bias1,
                   const float* __restrict__ bias2,
                   const float2* __restrict__ rope,
                   unsigned short* __restrict__ qb,
                   unsigned short* __restrict__ kb,
                   unsigned short* __restrict__ vb,
                   float* __restrict__ outf,
                   int Ntiles) {
  __shared__ __align__(16) unsigned short sA[2][2][8192];  // 64 KB
  __shared__ __align__(16) unsigned short sB[2][2][8192];  // 64 KB

  const int cpx = gridDim.x >> 3;
  const int bid = (blockIdx.x & 7) * cpx + (blockIdx.x >> 3);
  const int bm = bid / Ntiles, bn = bid % Ntiles;
  const int m0 = bm * 256, n0 = bn * 256;

  const int tid = threadIdx.x, w = tid >> 6, lane = tid & 63;
  const int wr = w >> 2, wc = w & 3;

  // staging bases: lane -> row w*8+(lane>>3), pre-swizzled k-granule
  const int sgr = ((lane & 7) ^ ((lane >> 3) & 7)) * 8;
  const unsigned short* gAs = A + ((size_t)m0 + w * 8 + (lane >> 3)) * KDIM + sgr;
  const unsigned short* gBs = Bw + ((size_t)n0 + w * 8 + (lane >> 3)) * KDIM + sgr;

  auto STGA = [&](int buf, int rh, int tk) {
    const unsigned short* src = gAs + ((size_t)rh * 128) * KDIM + tk * 64;
    gload_lds16(src, &sA[buf][rh][w * 512]);
    gload_lds16(src + (size_t)64 * KDIM, &sA[buf][rh][(8 + w) * 512]);
  };
  auto STGB = [&](int buf, int rh, int tk) {
    const unsigned short* src = gBs + ((size_t)rh * 128) * KDIM + tk * 64;
    gload_lds16(src, &sB[buf][rh][w * 512]);
    gload_lds16(src + (size_t)64 * KDIM, &sB[buf][rh][(8 + w) * 512]);
  };

  // read offsets (bytes within a 16KB unit) -- round-2 zero-conflict pattern
  const unsigned kx = (lane & 7) * 8, kq = (lane >> 4) * 8;
  const unsigned koff0 = 2u * ((0 * 32 + kq) ^ kx);
  const unsigned koff1 = 2u * ((1 * 32 + kq) ^ kx);
  const unsigned rowA = (unsigned)(wr * 64 + (lane & 15)) * 128;
  const unsigned rowB = (unsigned)(wc * 32 + (lane & 15)) * 128;

  f32x4 acc[8][4] = {};

  // prologue: A0(0),B0(0),A1(0),B1(0),A0(1),B0(1); all tile0 landed
  STGA(0, 0, 0); STGB(0, 0, 0); STGA(0, 1, 0); STGB(0, 1, 0);
  STGA(1, 0, 1); STGB(1, 0, 1);
  WAITV(4);
  SCHEDB; BARRIER;

#pragma unroll 1
  for (int t = 0; t < NT; ++t) {
    const int c = t & 1, nb = c ^ 1;
    const unsigned uA0 = ldsaddr(&sA[c][0][0]);
    const unsigned uA1 = ldsaddr(&sA[c][1][0]);
    const unsigned uB0 = ldsaddr(&sB[c][0][0]);
    const unsigned uB1 = ldsaddr(&sB[c][1][0]);
    bf16x8 a[4][2], b[2][2];

    // ---- P1: quadrant (mh0, nh0) ----
#pragma unroll
    for (int mi = 0; mi < 4; ++mi) {
      a[mi][0] = ds128(uA0 + rowA + mi * 2048 + koff0);
      a[mi][1] = ds128(uA0 + rowA + mi * 2048 + koff1);
    }
#pragma unroll
    for (int ni = 0; ni < 2; ++ni) {
      b[ni][0] = ds128(uB0 + rowB + ni * 2048 + koff0);
      b[ni][1] = ds128(uB0 + rowB + ni * 2048 + koff1);
    }
    if (t + 1 < NT) STGA(nb, 1, t + 1);
    SCHEDB; BARRIER; LGKM0; SCHEDB;
    PHASE_MFMA(0, 0, a, b)
    SCHEDB; BARRIER;

    // ---- P2: quadrant (mh0, nh1); a held in regs ----
#pragma unroll
    for (int ni = 0; ni < 2; ++ni) {
      b[ni][0] = ds128(uB1 + rowB + ni * 2048 + koff0);
      b[ni][1] = ds128(uB1 + rowB + ni * 2048 + koff1);
    }
    if (t + 1 < NT) STGB(nb, 1, t + 1);
    SCHEDB; BARRIER; LGKM0; SCHEDB;
    PHASE_MFMA(0, 1, a, b)
    SCHEDB; BARRIER;

    // ---- P3: quadrant (mh1, nh0) ----
#pragma unroll
    for (int mi = 0; mi < 4; ++mi) {
      a[mi][0] = ds128(uA1 + rowA + mi * 2048 + koff0);
      a[mi][1] = ds128(uA1 + rowA + mi * 2048 + koff1);
    }
#pragma unroll
    for (int ni = 0; ni < 2; ++ni) {
      b[ni][0] = ds128(uB0 + rowB + ni * 2048 + koff0);
      b[ni][1] = ds128(uB0 + rowB + ni * 2048 + koff1);
    }
    if (t + 2 < NT) STGA(c, 0, t + 2);
    SCHEDB; BARRIER; LGKM0; SCHEDB;
    PHASE_MFMA(1, 0, a, b)
    SCHEDB; BARRIER;

    // ---- P4: quadrant (mh1, nh1); a held ----
#pragma unroll
    for (int ni = 0; ni < 2; ++ni) {
      b[ni][0] = ds128(uB1 + rowB + ni * 2048 + koff0);
      b[ni][1] = ds128(uB1 + rowB + ni * 2048 + koff1);
    }
    if (t + 2 < NT) STGB(c, 0, t + 2);
    SCHEDB; BARRIER; LGKM0; SCHEDB;
    PHASE_MFMA(1, 1, a, b)
    SCHEDB;
    if (t < NT - 2) { WAITV(4); } else { WAITV(0); }
    BARRIER;
  }

  // epilogue; C/D layout: col = lane&15, row = (lane>>4)*4 + r  [m89/m91]
#pragma unroll
  for (int mi = 0; mi < 8; ++mi) {
#pragma unroll
    for (int ni = 0; ni < 4; ++ni) {
#pragma unroll
      for (int r = 0; r < 4; ++r) {
        const int row = m0 + (mi >> 2) * 128 + wr * 64 + (mi & 3) * 16 +
                        (lane >> 4) * 4 + r;
        const int col = n0 + (ni >> 1) * 128 + wc * 32 + (ni & 1) * 16 +
                        (lane & 15);
        float v = acc[mi][ni][r];
        if (MODE == 0) {
          const int id = col >> 10;        // 0=q 1=k 2=v (block-uniform)
          const int cgl = col & 1023;
          const float* bp = (id == 0) ? bias0 : (id == 1 ? bias1 : bias2);
          v += bp[cgl];
          const int si = row & 63;
          if (id < 2) {
            const float pv = __shfl_xor(v, 1);
            const float2 cs = rope[(si << 9) + (cgl >> 1)];
            v = v * cs.x + ((lane & 1) ? pv * cs.y : -pv * cs.y);
          }
          const int bi = row >> 6;
          const int h = cgl >> 6, dh = cgl & 63;
          const size_t off = (((size_t)bi * NH + h) * SEQ + si) * HD + dh;
          const unsigned short bfv = f2bf(v);
          if (id == 0) qb[off] = bfv;
          else if (id == 1) kb[off] = bfv;
          else vb[off] = bfv;
        } else {
          outf[(size_t)row * DM + col] = v + bias0[col];
        }
      }
    }
  }
}

// ---------------- attention: one block per (b,h); S=64, HD=64 ---------------
__global__ __launch_bounds__(256, 4)
void attn_kernel(const unsigned short* __restrict__ qb,
                 const unsigned short* __restrict__ kbuf,
                 const unsigned short* __restrict__ vbuf,
                 unsigned short* __restrict__ vals) {
  __shared__ __align__(16) unsigned short sQ[64 * 64];
  __shared__ __align__(16) unsigned short sK[64 * 64];
  __shared__ __align__(16) unsigned short sV[64 * 64];
  __shared__ __align__(16) unsigned short sP[64 * 64];
  const int bh = blockIdx.x;
  const int t = threadIdx.x, wave = t >> 6, lane = t & 63;
  const size_t base = (size_t)bh * 4096;

#pragma unroll
  for (int is = 0; is < 2; ++is) {
    const size_t go = base + is * 2048 + wave * 512 + (size_t)lane * 8;
    const int lo = is * 2048 + wave * 512;
    gload_lds16(qb + go, &sQ[lo]);
    gload_lds16(kbuf + go, &sK[lo]);
    gload_lds16(vbuf + go, &sV[lo]);
  }
  __syncthreads();

  f32x4 sacc[4] = {};
#pragma unroll
  for (int kk = 0; kk < 2; ++kk) {
    const int krow = kk * 32 + (lane >> 4) * 8;
    const bf16x8 aq = *reinterpret_cast<const bf16x8*>(
        &sQ[(wave * 16 + (lane & 15)) * 64 + krow]);
#pragma unroll
    for (int ni = 0; ni < 4; ++ni) {
      const bf16x8 bkf = *reinterpret_cast<const bf16x8*>(
          &sK[(ni * 16 + (lane & 15)) * 64 + krow]);
      sacc[ni] = __builtin_amdgcn_mfma_f32_16x16x32_bf16(aq, bkf, sacc[ni], 0, 0, 0);
    }
  }
#pragma unroll
  for (int ni = 0; ni < 4; ++ni) sacc[ni] *= 0.125f;

#pragma unroll
  for (int r = 0; r < 4; ++r) {
    float mx = sacc[0][r];
#pragma unroll
    for (int ni = 1; ni < 4; ++ni) mx = fmaxf(mx, sacc[ni][r]);
#pragma unroll
    for (int off = 8; off; off >>= 1) mx = fmaxf(mx, __shfl_xor(mx, off));
    float e[4]; float sum = 0.f;
#pragma unroll
    for (int ni = 0; ni < 4; ++ni) { e[ni] = __expf(sacc[ni][r] - mx); sum += e[ni]; }
#pragma unroll
    for (int off = 8; off; off >>= 1) sum += __shfl_xor(sum, off);
    const float inv = 1.0f / sum;
    const int rowl = wave * 16 + (lane >> 4) * 4 + r;
#pragma unroll
    for (int ni = 0; ni < 4; ++ni)
      sP[rowl * 64 + ni * 16 + (lane & 15)] = f2bf(e[ni] * inv);
  }
  __syncthreads();

  f32x4 vacc[4] = {};
#pragma unroll
  for (int kk = 0; kk < 2; ++kk) {
    const int kb0 = kk * 32 + (lane >> 4) * 8;
    const bf16x8 ap = *reinterpret_cast<const bf16x8*>(
        &sP[(wave * 16 + (lane & 15)) * 64 + kb0]);
#pragma unroll
    for (int ni = 0; ni < 4; ++ni) {
      bf16x8 bvv;
      const int dh = ni * 16 + (lane & 15);
#pragma unroll
      for (int i = 0; i < 8; ++i)
        bvv[i] = __builtin_bit_cast(__bf16, sV[(kb0 + i) * 64 + dh]);
      vacc[ni] = __builtin_amdgcn_mfma_f32_16x16x32_bf16(ap, bvv, vacc[ni], 0, 0, 0);
    }
  }

  const int b = bh >> 4, h = bh & 15;
#pragma unroll
  for (int ni = 0; ni < 4; ++ni) {
#pragma unroll
    for (int r = 0; r < 4; ++r) {
      const int si = wave * 16 + (lane >> 4) * 4 + r;
      const int dh = ni * 16 + (lane & 15);
      vals[((size_t)b * SEQ + si) * DM + h * HD + dh] = f2bf(vacc[ni][r]);
    }
  }
}

// ---------------------------------------------------------------------------
extern "C" void kernel_launch(void* const* d_in, const int* in_sizes, int n_in,
                              void* d_out, int out_size, void* d_ws, size_t ws_size,
                              hipStream_t stream) {
  (void)in_sizes; (void)n_in; (void)out_size; (void)ws_size;
  const float* x  = (const float*)d_in[0];
  const float* Wq = (const float*)d_in[1];
  const float* bq = (const float*)d_in[2];
  const float* Wk = (const float*)d_in[3];
  const float* bk = (const float*)d_in[4];
  const float* Wv = (const float*)d_in[5];
  const float* bv = (const float*)d_in[6];
  const float* Wo = (const float*)d_in[7];
  const float* bo = (const float*)d_in[8];
  float* out = (float*)d_out;

  unsigned short* xb   = (unsigned short*)d_ws;
  unsigned short* wb   = xb + (size_t)MROWS * DM;
  unsigned short* qbuf = wb + 4ull * DM * DM;
  unsigned short* kbuf = qbuf + (size_t)MROWS * DM;
  unsigned short* vbuf = kbuf + (size_t)MROWS * DM;
  float2* rope = (float2*)(vbuf + (size_t)MROWS * DM);

  convert_all_kernel<<<2048, 256, 0, stream>>>(x, Wq, Wk, Wv, Wo, xb);
  rope_table_kernel<<<(SEQ * 512 + 255) / 256, 256, 0, stream>>>(rope);

  // QKV: M=32768, N=3072, K=1024 -> 128 x 12 = 1536 blocks
  gemm8q_kernel<0><<<(MROWS / 256) * (3 * DM / 256), 512, 0, stream>>>(
      xb, wb, bq, bk, bv, rope, qbuf, kbuf, vbuf, nullptr, 3 * DM / 256);

  attn_kernel<<<BATCH * NH, 256, 0, stream>>>(qbuf, kbuf, vbuf, xb);

  // O-proj: M=32768, N=1024, K=1024 -> 128 x 4 = 512 blocks
  gemm8q_kernel<1><<<(MROWS / 256) * (DM / 256), 512, 0, stream>>>(
      xb, wb + 3ull * DM * DM, bo, nullptr, nullptr, nullptr,
      nullptr, nullptr, nullptr, out, DM / 256);
}